// Round 4
// baseline (190.637 us; speedup 1.0000x reference)
//
#include <hip/hip_runtime.h>

// SSIM, 64 slices of 512x512, 11x11 uniform window (separable box), zero pad.
// R4: wave-autonomous design — NO __syncthreads, no LDS slab.
//  - each wave owns an 8-output-row band x full 512 cols (8 cols/lane).
//  - vertical running box sums in registers (5 quantities x 8 cols);
//    the "subtract row r-11" values are re-loaded from global (L2/L3-hot;
//    whole input fits in the 256 MB Infinity Cache).
//  - horizontal 11-box sum in-register: 10 lane shuffles bring the 5+5
//    neighbor column sums, then a sliding-window sum. No LDS bank traffic.
//  - per-wave partial -> global; tiny finalize kernel reduces 4096 partials.

constexpr int IMG    = 512;
constexpr int BAND   = 8;                       // output rows per wave
constexpr int BANDS  = IMG / BAND;              // 64
constexpr int WPB    = 4;                       // waves per block
constexpr int BX     = BANDS / WPB;             // 16 blocks in x
constexpr float WSCALE = 1.0f / 121.0f;
constexpr float C1F = 1e-4f;                    // 0.01^2
constexpr float C2F = 9e-4f;                    // 0.03^2

__device__ __forceinline__ float shl1(float v, int lane) {  // lane g-1's v, 0 at g==0
  const float t = __shfl_up(v, 1, 64);
  return lane == 0 ? 0.f : t;
}
__device__ __forceinline__ float shr1(float v, int lane) {  // lane g+1's v, 0 at g==63
  const float t = __shfl_down(v, 1, 64);
  return lane == 63 ? 0.f : t;
}

// horizontal 11-wide box sum of per-column sums c[0..7] (cols 8g..8g+7),
// with zero padding outside [0,512). h[j] = sum cols (8g+j-5 .. 8g+j+5).
__device__ __forceinline__ void hbox11(const float c[8], int lane, float h[8]) {
  float w[18];
  w[0] = shl1(c[3], lane);
  w[1] = shl1(c[4], lane);
  w[2] = shl1(c[5], lane);
  w[3] = shl1(c[6], lane);
  w[4] = shl1(c[7], lane);
#pragma unroll
  for (int k = 0; k < 8; ++k) w[5 + k] = c[k];
  w[13] = shr1(c[0], lane);
  w[14] = shr1(c[1], lane);
  w[15] = shr1(c[2], lane);
  w[16] = shr1(c[3], lane);
  w[17] = shr1(c[4], lane);
  float s = w[0];
#pragma unroll
  for (int k = 1; k <= 10; ++k) s += w[k];
  h[0] = s;
#pragma unroll
  for (int j = 1; j < 8; ++j) { s += w[j + 10] - w[j - 1]; h[j] = s; }
}

template <bool ATOMIC>
__global__ __launch_bounds__(256, 4) void ssim_main(const float* __restrict__ x,
                                                    const float* __restrict__ y,
                                                    float* __restrict__ out_ws) {
  const int tid  = threadIdx.x;
  const int lane = tid & 63;
  const int wv   = tid >> 6;
  const int band = blockIdx.x * WPB + wv;   // 0..63
  const int z    = blockIdx.y;              // 0..63
  const int O0   = band * BAND;             // first output row
  const int r0   = O0 - 5;                  // first streamed input row
  const float* xs = x + (size_t)z * IMG * IMG;
  const float* ys = y + (size_t)z * IMG * IMG;
  const int c0   = lane * 8;

  float cX[8]  = {0.f,0.f,0.f,0.f,0.f,0.f,0.f,0.f};
  float cY[8]  = {0.f,0.f,0.f,0.f,0.f,0.f,0.f,0.f};
  float cXX[8] = {0.f,0.f,0.f,0.f,0.f,0.f,0.f,0.f};
  float cYY[8] = {0.f,0.f,0.f,0.f,0.f,0.f,0.f,0.f};
  float cXY[8] = {0.f,0.f,0.f,0.f,0.f,0.f,0.f,0.f};
  float acc = 0.f;

  auto add_row = [&](int gr) {
    if ((unsigned)gr < (unsigned)IMG) {       // wave-uniform branch
      const float4 a0 = *(const float4*)(xs + (size_t)gr * IMG + c0);
      const float4 a1 = *(const float4*)(xs + (size_t)gr * IMG + c0 + 4);
      const float4 b0 = *(const float4*)(ys + (size_t)gr * IMG + c0);
      const float4 b1 = *(const float4*)(ys + (size_t)gr * IMG + c0 + 4);
      float vx[8] = {a0.x, a0.y, a0.z, a0.w, a1.x, a1.y, a1.z, a1.w};
      float vy[8] = {b0.x, b0.y, b0.z, b0.w, b1.x, b1.y, b1.z, b1.w};
#pragma unroll
      for (int k = 0; k < 8; ++k) {
        cX[k] += vx[k];
        cY[k] += vy[k];
        cXX[k] = fmaf(vx[k], vx[k], cXX[k]);
        cYY[k] = fmaf(vy[k], vy[k], cYY[k]);
        cXY[k] = fmaf(vx[k], vy[k], cXY[k]);
      }
    }
  };
  auto sub_row = [&](int gr) {
    if (gr >= r0 && (unsigned)gr < (unsigned)IMG) {   // rows <r0 or >=512 were never added
      const float4 a0 = *(const float4*)(xs + (size_t)gr * IMG + c0);
      const float4 a1 = *(const float4*)(xs + (size_t)gr * IMG + c0 + 4);
      const float4 b0 = *(const float4*)(ys + (size_t)gr * IMG + c0);
      const float4 b1 = *(const float4*)(ys + (size_t)gr * IMG + c0 + 4);
      float vx[8] = {a0.x, a0.y, a0.z, a0.w, a1.x, a1.y, a1.z, a1.w};
      float vy[8] = {b0.x, b0.y, b0.z, b0.w, b1.x, b1.y, b1.z, b1.w};
#pragma unroll
      for (int k = 0; k < 8; ++k) {
        cX[k] -= vx[k];
        cY[k] -= vy[k];
        cXX[k] = fmaf(-vx[k], vx[k], cXX[k]);
        cYY[k] = fmaf(-vy[k], vy[k], cYY[k]);
        cXY[k] = fmaf(-vx[k], vy[k], cXY[k]);
      }
    }
  };
  auto emit_row = [&]() {
    float hX[8], hY[8], hXX[8], hYY[8], hXY[8];
    hbox11(cX,  lane, hX);
    hbox11(cY,  lane, hY);
    hbox11(cXX, lane, hXX);
    hbox11(cYY, lane, hYY);
    hbox11(cXY, lane, hXY);
#pragma unroll
    for (int j = 0; j < 8; ++j) {
      const float mu_x = hX[j] * WSCALE;
      const float mu_y = hY[j] * WSCALE;
      const float ex2  = hXX[j] * WSCALE;
      const float ey2  = hYY[j] * WSCALE;
      const float exy  = hXY[j] * WSCALE;
      const float mxx = mu_x * mu_x;
      const float myy = mu_y * mu_y;
      const float mxy = mu_x * mu_y;
      const float num = fmaf(2.f, mxy, C1F) * fmaf(2.f, exy - mxy, C2F);
      const float den = (mxx + myy + C1F) * ((ex2 - mxx) + (ey2 - myy) + C2F);
      acc += num * __builtin_amdgcn_rcpf(den);
    }
  };

  // spin-up: accumulate rows r0 .. r0+9 (out-of-range rows contribute zero)
  for (int i = 0; i < 10; ++i) add_row(r0 + i);

  // first output row: window rows r0..r0+10 -> output O0
  add_row(r0 + 10);
  emit_row();

  // steady state: slide window one row at a time, outputs O0+1 .. O0+7
  for (int i = 11; i < 18; ++i) {
    add_row(r0 + i);
    sub_row(r0 + i - 11);
    emit_row();
  }

  // per-wave reduction, one partial per wave (no cross-wave sync needed)
#pragma unroll
  for (int off = 32; off > 0; off >>= 1) acc += __shfl_down(acc, off, 64);
  if (lane == 0) {
    if (ATOMIC) {
      atomicAdd(out_ws, acc);
    } else {
      out_ws[(size_t)z * BANDS + band] = acc;
    }
  }
}

__global__ void ssim_finalize(const float* __restrict__ partials, int n,
                              float* __restrict__ out) {
  __shared__ float wsum[4];
  float acc = 0.f;
  for (int i = threadIdx.x; i < n; i += 256) acc += partials[i];
#pragma unroll
  for (int off = 32; off > 0; off >>= 1) acc += __shfl_down(acc, off, 64);
  if ((threadIdx.x & 63) == 0) wsum[threadIdx.x >> 6] = acc;
  __syncthreads();
  if (threadIdx.x == 0) {
    const float t = wsum[0] + wsum[1] + wsum[2] + wsum[3];
    out[0] = 1.0f - t * (1.0f / (64.0f * 512.0f * 512.0f));
  }
}

__global__ void ssim_zero(float* p) {
  if (threadIdx.x == 0) p[0] = 0.f;
}

__global__ void ssim_finalize_atomic(const float* __restrict__ accp,
                                     float* __restrict__ out) {
  if (threadIdx.x == 0)
    out[0] = 1.0f - accp[0] * (1.0f / (64.0f * 512.0f * 512.0f));
}

extern "C" void kernel_launch(void* const* d_in, const int* in_sizes, int n_in,
                              void* d_out, int out_size, void* d_ws, size_t ws_size,
                              hipStream_t stream) {
  const float* x = (const float*)d_in[0];
  const float* y = (const float*)d_in[1];
  // d_in[2]: uniform 1/121 window, folded into WSCALE.
  float* out = (float*)d_out;

  dim3 grid(BX, 64);      // 16 x 64 = 1024 blocks, 4096 independent waves
  dim3 block(256);
  const int npart = BANDS * 64;   // one partial per wave = 4096

  if (ws_size >= (size_t)npart * sizeof(float)) {
    float* partials = (float*)d_ws;
    ssim_main<false><<<grid, block, 0, stream>>>(x, y, partials);
    ssim_finalize<<<1, 256, 0, stream>>>(partials, npart, out);
  } else {
    float* accp = (float*)d_ws;
    ssim_zero<<<1, 64, 0, stream>>>(accp);
    ssim_main<true><<<grid, block, 0, stream>>>(x, y, accp);
    ssim_finalize_atomic<<<1, 64, 0, stream>>>(accp, out);
  }
}